// Round 12
// baseline (157.760 us; speedup 1.0000x reference)
//
#include <hip/hip_runtime.h>

#define QDIM 192
#define KDIM 64
#define CDIM 256
#define NCOLS 640   // virtual col layout: [q 0:256 | k 256:512 | v 512:576 | s 576:640]
#define DOUT 128
#define CAP 128     // adjacency slots per node; deg ~ Poisson(32), P(>=128) ~ 1e-40
#define NEG_INF __int_as_float(0xFF800000)

typedef _Float16 hf2 __attribute__((ext_vector_type(2)));
typedef _Float16 half4 __attribute__((ext_vector_type(4)));
typedef _Float16 half8 __attribute__((ext_vector_type(8)));
typedef float floatx4 __attribute__((ext_vector_type(4)));

#if defined(__has_builtin)
#if __has_builtin(__builtin_amdgcn_fdot2)
#define HAVE_FDOT2 1
#endif
#endif

__device__ __forceinline__ hf2 bc_h2(unsigned u) { return __builtin_bit_cast(hf2, u); }

__device__ __forceinline__ float dot2acc(hf2 a, hf2 b, float c) {
#ifdef HAVE_FDOT2
    return __builtin_amdgcn_fdot2(a, b, c, false);
#else
    return c + (float)a[0] * (float)b[0] + (float)a[1] * (float)b[1];
#endif
}

// map virtual output col j (0..639) -> source W matrix + its column
__device__ __forceinline__ void wmap(int j, const float* Wq, const float* Wk,
                                     const float* Wv, const float* Ws,
                                     const float** W, int* wcol) {
    if (j < 256)      { *W = Wq; *wcol = j; }
    else if (j < 512) { *W = Wk; *wcol = j - 256; }
    else if (j < 576) { *W = Wv; *wcol = QDIM + (j - 512); }
    else              { *W = Ws; *wcol = QDIM + (j - 576); }
}

// prep: Qh = fp16(query) [N x 192]; BhT[n][k] = fp16(W(k, wcol(n))) [640 x 192]; deg = 0
__global__ __launch_bounds__(256) void prep_kernel(
        const float* __restrict__ query,
        const float* Wq, const float* Wk, const float* Wv, const float* Ws,
        _Float16* __restrict__ Qh, _Float16* __restrict__ BhT,
        int* __restrict__ deg, int qchunks, int N) {
    int t = blockIdx.x * blockDim.x + threadIdx.x;
    if (t < qchunks) {
        float4 v = ((const float4*)query)[t];
        half4 h = { (_Float16)v.x, (_Float16)v.y, (_Float16)v.z, (_Float16)v.w };
        ((half4*)Qh)[t] = h;
        return;
    }
    t -= qchunks;
    if (t < NCOLS * QDIM) {
        int n = t / QDIM, k = t % QDIM;
        const float* W; int wc;
        wmap(n, Wq, Wk, Wv, Ws, &W, &wc);
        BhT[t] = (_Float16)W[k * CDIM + wc];
        return;
    }
    t -= NCOLS * QDIM;
    if (t < N) deg[t] = 0;
}

// LDS-free fused MFMA node-GEMM + edge bucket-scatter.
//  - piggyback: thread-strided capped bucket scatter over all edges
//  - A fragments: 6 x 16B direct global loads from Qh, held in VGPRs for both tiles
//  - B fragments: direct global loads from BhT (0.24 MB, L2-resident)
//  - epilogue adds one-hot row W[192+key_idx][.] + bias, routes Q/K/V (f16), S (f32)
__global__ __launch_bounds__(256) void gemm_scatter(
        const _Float16* __restrict__ Qh, const _Float16* __restrict__ BhT,
        const int* __restrict__ key_idx,
        const float* Wq, const float* bq, const float* Wk, const float* bk,
        const float* Wv, const float* bv, const float* Ws, const float* bs,
        const int* __restrict__ esrc, const int* __restrict__ edst,
        int* __restrict__ deg, int* __restrict__ adj, int E,
        _Float16* __restrict__ Qbuf, _Float16* __restrict__ Kbuf,
        _Float16* __restrict__ Vbuf, float* __restrict__ Sbuf, int N) {
    int tid = threadIdx.x;
    int bm = blockIdx.x * 64;

    // --- piggyback edge scatter (independent of GEMM data; overlaps load latency) ---
    {
        int total = gridDim.x * gridDim.y * 256;
        int gid = (blockIdx.y * gridDim.x + blockIdx.x) * 256 + tid;
        for (int e = gid; e < E; e += total) {
            int d = edst[e];
            int slot = atomicAdd(&deg[d], 1);
            if (slot < CAP) adj[d * CAP + slot] = esrc[e];
        }
    }

    int w = tid >> 6, l = tid & 63;
    int lrow = l & 15, quad = l >> 4;

    // A fragments for this wave's 16 rows: m = lrow, k = ks*32 + quad*8
    int gr_a = bm + w * 16 + lrow;
    half8 af[6];
    {
        const _Float16* ap = Qh + (size_t)gr_a * QDIM + quad * 8;
        bool ok = (gr_a < N);
        #pragma unroll
        for (int ks = 0; ks < 6; ks++) {
            half8 z = { (_Float16)0.f, (_Float16)0.f, (_Float16)0.f, (_Float16)0.f,
                        (_Float16)0.f, (_Float16)0.f, (_Float16)0.f, (_Float16)0.f };
            af[ks] = ok ? *(const half8*)(ap + ks * 32) : z;
        }
    }

    int ki[4];
    #pragma unroll
    for (int reg = 0; reg < 4; reg++) {
        int gr = bm + w * 16 + quad * 4 + reg;
        ki[reg] = (gr < N) ? key_idx[gr] : 0;
    }

    // --- two 64-col bn-tiles per block ---
    #pragma unroll
    for (int t = 0; t < 2; t++) {
        int bn = blockIdx.y * 128 + t * 64;
        const float* Wb; const float* bvec; int wc0;
        if (bn < 256)      { Wb = Wq; bvec = bq; wc0 = bn; }
        else if (bn < 512) { Wb = Wk; bvec = bk; wc0 = bn - 256; }
        else if (bn < 576) { Wb = Wv; bvec = bv; wc0 = QDIM + (bn - 512); }
        else               { Wb = Ws; bvec = bs; wc0 = QDIM + (bn - 576); }

        floatx4 acc[4] = {{0.f,0.f,0.f,0.f},{0.f,0.f,0.f,0.f},{0.f,0.f,0.f,0.f},{0.f,0.f,0.f,0.f}};
        // B fragment: n = bn + nt*16 + lrow, k = ks*32 + quad*8 (16B direct loads)
        const _Float16* bp = BhT + (size_t)(bn + lrow) * QDIM + quad * 8;
        #pragma unroll
        for (int ks = 0; ks < 6; ks++) {
            #pragma unroll
            for (int nt = 0; nt < 4; nt++) {
                half8 bf = *(const half8*)(bp + (size_t)nt * 16 * QDIM + ks * 32);
                acc[nt] = __builtin_amdgcn_mfma_f32_16x16x32_f16(af[ks], bf, acc[nt], 0, 0, 0);
            }
        }

        // epilogue: D(row = bm + w*16 + quad*4 + reg, col = bn + nt*16 + lrow)
        #pragma unroll
        for (int nt = 0; nt < 4; nt++) {
            int gc = bn + nt * 16 + lrow;
            int wc = wc0 + nt * 16 + lrow;
            float bias = bvec[wc];
            #pragma unroll
            for (int reg = 0; reg < 4; reg++) {
                int gr = bm + w * 16 + quad * 4 + reg;
                if (gr < N) {
                    float v = acc[nt][reg] + Wb[(size_t)(QDIM + ki[reg]) * CDIM + wc] + bias;
                    if (gc < 256)      Qbuf[(size_t)gr * 256 + gc] = (_Float16)v;
                    else if (gc < 512) Kbuf[(size_t)gr * 256 + (gc - 256)] = (_Float16)v;
                    else if (gc < 576) Vbuf[(size_t)gr * KDIM + (gc - 512)] = (_Float16)v;
                    else               Sbuf[(size_t)gr * KDIM + (gc - 576)] = v;
                }
            }
        }
    }
}

// 1 wave per output-run (masked node): 16-lane groups, 4 edges in flight,
// private online-softmax state per group, single end-merge,
// fused relu + 64x128 GEMV into d_out. 4 rows/block.
__global__ __launch_bounds__(256) void attend_out(
        const _Float16* __restrict__ Qbuf, const _Float16* __restrict__ Kbuf,
        const _Float16* __restrict__ Vbuf, const float* __restrict__ Sbuf,
        const int* __restrict__ deg, const int* __restrict__ adj,
        const int* __restrict__ mask, const float* __restrict__ Wo,
        const float* __restrict__ bo, float* __restrict__ out, int M) {
    int w = threadIdx.x >> 6, lane = threadIdx.x & 63;
    int r = blockIdx.x * 4 + w;
    if (r >= M) return;
    int node = mask[r];
    if (r > 0 && mask[r - 1] == node) return;   // duplicate run: start-wave writes it
    int l = lane & 15, g = lane >> 4;

    const uint4* qp = (const uint4*)(Qbuf + (size_t)node * 256 + l * 16);
    uint4 qa = qp[0], qb = qp[1];
    hf2 qh[8] = { bc_h2(qa.x), bc_h2(qa.y), bc_h2(qa.z), bc_h2(qa.w),
                  bc_h2(qb.x), bc_h2(qb.y), bc_h2(qb.z), bc_h2(qb.w) };

    int dn = min(deg[node], CAP);
    const int* arow = adj + (size_t)node * CAP;

    // private per-group state: m, dsum uniform in group; acc = 4 V-cols per lane
    float m = NEG_INF, dsum = 0.f;
    float a0 = 0.f, a1 = 0.f, a2 = 0.f, a3 = 0.f;
    for (int i = g; i < dn; i += 4) {
        int s = arow[i];
        const uint4* kp = (const uint4*)(Kbuf + (size_t)s * 256 + l * 16);
        uint4 ka = kp[0], kb = kp[1];
        float d = 0.f;
        d = dot2acc(bc_h2(ka.x), qh[0], d);
        d = dot2acc(bc_h2(ka.y), qh[1], d);
        d = dot2acc(bc_h2(ka.z), qh[2], d);
        d = dot2acc(bc_h2(ka.w), qh[3], d);
        d = dot2acc(bc_h2(kb.x), qh[4], d);
        d = dot2acc(bc_h2(kb.y), qh[5], d);
        d = dot2acc(bc_h2(kb.z), qh[6], d);
        d = dot2acc(bc_h2(kb.w), qh[7], d);
        d += __shfl_xor(d, 1, 64);
        d += __shfl_xor(d, 2, 64);
        d += __shfl_xor(d, 4, 64);
        d += __shfl_xor(d, 8, 64);
        float sc = d * 0.0625f;              // 1/sqrt(256)
        float m_new = fmaxf(m, sc);
        float scale = __expf(m - m_new);     // first edge: exp(-inf)=0
        float p = __expf(sc - m_new);
        dsum = dsum * scale + p;
        uint2 vv = *(const uint2*)(Vbuf + (size_t)s * KDIM + l * 4);
        hf2 v01 = bc_h2(vv.x), v23 = bc_h2(vv.y);
        a0 = a0 * scale + p * (float)v01[0];
        a1 = a1 * scale + p * (float)v01[1];
        a2 = a2 * scale + p * (float)v23[0];
        a3 = a3 * scale + p * (float)v23[1];
        m = m_new;
    }

    // merge the 4 groups (m, dsum group-uniform)
    float Mx = fmaxf(m, __shfl_xor(m, 16, 64));
    Mx = fmaxf(Mx, __shfl_xor(Mx, 32, 64));
    float wgt = (m == NEG_INF) ? 0.f : __expf(m - Mx);   // empty group / dn==0
    float ds = dsum * wgt;
    ds += __shfl_xor(ds, 16, 64);
    ds += __shfl_xor(ds, 32, 64);
    a0 *= wgt; a1 *= wgt; a2 *= wgt; a3 *= wgt;
    a0 += __shfl_xor(a0, 16, 64); a0 += __shfl_xor(a0, 32, 64);
    a1 += __shfl_xor(a1, 16, 64); a1 += __shfl_xor(a1, 32, 64);
    a2 += __shfl_xor(a2, 16, 64); a2 += __shfl_xor(a2, 32, 64);
    a3 += __shfl_xor(a3, 16, 64); a3 += __shfl_xor(a3, 32, 64);
    float inv = 1.f / (ds + 1e-16f);

    // h cols l*4..l*4+3 (identical across groups)
    float4 s4 = *((const float4*)(Sbuf + (size_t)node * KDIM + l * 4));
    float h0 = fmaxf(a0 * inv + s4.x, 0.f);
    float h1 = fmaxf(a1 * inv + s4.y, 0.f);
    float h2 = fmaxf(a2 * inv + s4.z, 0.f);
    float h3 = fmaxf(a3 * inv + s4.w, 0.f);

    // GEMV: out(row) = h @ Wo + bo
    float o0 = bo[lane], o1 = bo[lane + 64];
    #pragma unroll
    for (int c = 0; c < KDIM; c++) {
        float hc = (c & 3) == 0 ? h0 : (c & 3) == 1 ? h1 : (c & 3) == 2 ? h2 : h3;
        float hv = __shfl(hc, c >> 2, 64);
        o0 += hv * Wo[c * DOUT + lane];
        o1 += hv * Wo[c * DOUT + 64 + lane];
    }
    int rr = r;
    do {
        out[(size_t)rr * DOUT + lane] = o0;
        out[(size_t)rr * DOUT + 64 + lane] = o1;
        rr++;
    } while (rr < M && mask[rr] == node);
}

extern "C" void kernel_launch(void* const* d_in, const int* in_sizes, int n_in,
                              void* d_out, int out_size, void* d_ws, size_t ws_size,
                              hipStream_t stream) {
    const float* query    = (const float*)d_in[0];
    const int* key_idx    = (const int*)d_in[1];
    const int* edge_index = (const int*)d_in[2];
    const int* mask_idx   = (const int*)d_in[3];
    const float* Wq = (const float*)d_in[4];
    const float* bq = (const float*)d_in[5];
    const float* Wk = (const float*)d_in[6];
    const float* bk = (const float*)d_in[7];
    const float* Wv = (const float*)d_in[8];
    const float* bv = (const float*)d_in[9];
    const float* Ws = (const float*)d_in[10];
    const float* bs = (const float*)d_in[11];
    const float* Wo = (const float*)d_in[12];
    const float* bo = (const float*)d_in[13];

    int N = in_sizes[0] / QDIM;
    int E = in_sizes[2] / 2;
    int M = in_sizes[3];
    const int* esrc = edge_index;
    const int* edst = edge_index + E;

    char* wsb = (char*)d_ws;
    size_t off = 0;
    auto alloc = [&](size_t nbytes) { char* p = wsb + off; off += (nbytes + 15) & ~15ull; return p; };
    _Float16* Qh   = (_Float16*)alloc((size_t)N * QDIM * 2);
    _Float16* BhT  = (_Float16*)alloc((size_t)NCOLS * QDIM * 2);
    _Float16* Qbuf = (_Float16*)alloc((size_t)N * 256 * 2);
    _Float16* Kbuf = (_Float16*)alloc((size_t)N * 256 * 2);
    _Float16* Vbuf = (_Float16*)alloc((size_t)N * KDIM * 2);
    float* Sbuf    = (float*)alloc((size_t)N * KDIM * 4);
    int*   deg     = (int*)alloc((size_t)N * 4);
    int*   adj     = (int*)alloc((size_t)N * CAP * 4);

    int qchunks = N * QDIM / 4;   // float4 chunks of query
    int prep_elems = qchunks + NCOLS * QDIM + N;
    prep_kernel<<<(prep_elems + 255) / 256, 256, 0, stream>>>(
        query, Wq, Wk, Wv, Ws, Qh, BhT, deg, qchunks, N);

    dim3 ggrid((N + 63) / 64, 5);   // 640 cols = 5 x (2 tiles of 64)
    gemm_scatter<<<ggrid, 256, 0, stream>>>(Qh, BhT, key_idx, Wq, bq, Wk, bk, Wv, bv,
                                            Ws, bs, esrc, edst, deg, adj, E,
                                            Qbuf, Kbuf, Vbuf, Sbuf, N);

    attend_out<<<(M + 3) / 4, 256, 0, stream>>>(Qbuf, Kbuf, Vbuf, Sbuf, deg, adj,
                                                mask_idx, Wo, bo, (float*)d_out, M);
}

// Round 13
// 154.632 us; speedup vs baseline: 1.0202x; 1.0202x over previous
//
#include <hip/hip_runtime.h>

#define QDIM 192
#define KDIM 64
#define CDIM 256
#define NCOLS 640   // virtual col layout: [q 0:256 | k 256:512 | v 512:576 | s 576:640]
#define DOUT 128
#define CAP 128     // adjacency slots per node; deg ~ Poisson(32), P(>=128) ~ 1e-40
#define NEG_INF __int_as_float(0xFF800000)

typedef _Float16 hf2 __attribute__((ext_vector_type(2)));
typedef _Float16 half4 __attribute__((ext_vector_type(4)));
typedef _Float16 half8 __attribute__((ext_vector_type(8)));
typedef float floatx4 __attribute__((ext_vector_type(4)));

#if defined(__has_builtin)
#if __has_builtin(__builtin_amdgcn_fdot2)
#define HAVE_FDOT2 1
#endif
#endif

__device__ __forceinline__ hf2 bc_h2(unsigned u) { return __builtin_bit_cast(hf2, u); }

__device__ __forceinline__ float dot2acc(hf2 a, hf2 b, float c) {
#ifdef HAVE_FDOT2
    return __builtin_amdgcn_fdot2(a, b, c, false);
#else
    return c + (float)a[0] * (float)b[0] + (float)a[1] * (float)b[1];
#endif
}

// map virtual output col j (0..639) -> source W matrix + its column
__device__ __forceinline__ void wmap(int j, const float* Wq, const float* Wk,
                                     const float* Wv, const float* Ws,
                                     const float** W, int* wcol) {
    if (j < 256)      { *W = Wq; *wcol = j; }
    else if (j < 512) { *W = Wk; *wcol = j - 256; }
    else if (j < 576) { *W = Wv; *wcol = QDIM + (j - 512); }
    else              { *W = Ws; *wcol = QDIM + (j - 576); }
}

// prep: Qh = fp16(query); BhT[n][k] = fp16(W(k, wcol(n))); deg = INT_MIN sentinel
__global__ __launch_bounds__(256) void prep_kernel(
        const float* __restrict__ query,
        const float* Wq, const float* Wk, const float* Wv, const float* Ws,
        _Float16* __restrict__ Qh, _Float16* __restrict__ BhT,
        int* __restrict__ deg, int qchunks, int N) {
    int t = blockIdx.x * blockDim.x + threadIdx.x;
    if (t < qchunks) {
        float4 v = ((const float4*)query)[t];
        half4 h = { (_Float16)v.x, (_Float16)v.y, (_Float16)v.z, (_Float16)v.w };
        ((half4*)Qh)[t] = h;
        return;
    }
    t -= qchunks;
    if (t < NCOLS * QDIM) {
        int n = t / QDIM, k = t % QDIM;
        const float* W; int wc;
        wmap(n, Wq, Wk, Wv, Ws, &W, &wc);
        BhT[t] = (_Float16)W[k * CDIM + wc];
        return;
    }
    t -= NCOLS * QDIM;
    if (t < N) deg[t] = (int)0x80000000;   // INT_MIN: unmasked sentinel
}

// LDS-free MFMA node GEMM, one 64x64 tile per block, grid (N/64, 10).
//  - piggyback: deg[mask[...]] = 0
//  - A fragments: 6 x 16B direct global loads from Qh (held in VGPRs)
//  - B fragments: direct global loads from BhT (0.24 MB, L2-resident)
//  - epilogue adds one-hot row W[192+key_idx][.] + bias, routes Q/K/V (f16), S (f32)
__global__ __launch_bounds__(256) void gemm_nodes(
        const _Float16* __restrict__ Qh, const _Float16* __restrict__ BhT,
        const int* __restrict__ key_idx,
        const float* Wq, const float* bq, const float* Wk, const float* bk,
        const float* Wv, const float* bv, const float* Ws, const float* bs,
        const int* __restrict__ mask, int M, int* __restrict__ deg,
        _Float16* __restrict__ Qbuf, _Float16* __restrict__ Kbuf,
        _Float16* __restrict__ Vbuf, float* __restrict__ Sbuf, int N) {
    int tid = threadIdx.x;
    int bm = blockIdx.x * 64;
    int bn = blockIdx.y * 64;

    // piggyback masked-node marking (before scatter dispatch)
    int gid = (blockIdx.y * gridDim.x + blockIdx.x) * 256 + tid;
    if (gid < M) deg[mask[gid]] = 0;

    const float* Wb; const float* bvec; int wc0;
    if (bn < 256)      { Wb = Wq; bvec = bq; wc0 = bn; }
    else if (bn < 512) { Wb = Wk; bvec = bk; wc0 = bn - 256; }
    else if (bn < 576) { Wb = Wv; bvec = bv; wc0 = QDIM + (bn - 512); }
    else               { Wb = Ws; bvec = bs; wc0 = QDIM + (bn - 576); }

    int w = tid >> 6, l = tid & 63;
    int lrow = l & 15, quad = l >> 4;

    // A fragments: m = lrow, k = ks*32 + quad*8
    int gr_a = bm + w * 16 + lrow;
    half8 af[6];
    {
        const _Float16* ap = Qh + (size_t)gr_a * QDIM + quad * 8;
        bool ok = (gr_a < N);
        #pragma unroll
        for (int ks = 0; ks < 6; ks++) {
            half8 z = { (_Float16)0.f, (_Float16)0.f, (_Float16)0.f, (_Float16)0.f,
                        (_Float16)0.f, (_Float16)0.f, (_Float16)0.f, (_Float16)0.f };
            af[ks] = ok ? *(const half8*)(ap + ks * 32) : z;
        }
    }

    floatx4 acc[4] = {{0.f,0.f,0.f,0.f},{0.f,0.f,0.f,0.f},{0.f,0.f,0.f,0.f},{0.f,0.f,0.f,0.f}};
    const _Float16* bp = BhT + (size_t)(bn + lrow) * QDIM + quad * 8;
    #pragma unroll
    for (int ks = 0; ks < 6; ks++) {
        #pragma unroll
        for (int nt = 0; nt < 4; nt++) {
            half8 bf = *(const half8*)(bp + (size_t)nt * 16 * QDIM + ks * 32);
            acc[nt] = __builtin_amdgcn_mfma_f32_16x16x32_f16(af[ks], bf, acc[nt], 0, 0, 0);
        }
    }

    // epilogue: D(row = bm + w*16 + quad*4 + reg, col = bn + nt*16 + lrow)
    int ki[4];
    #pragma unroll
    for (int reg = 0; reg < 4; reg++) {
        int gr = bm + w * 16 + quad * 4 + reg;
        ki[reg] = (gr < N) ? key_idx[gr] : 0;
    }
    #pragma unroll
    for (int nt = 0; nt < 4; nt++) {
        int gc = bn + nt * 16 + lrow;
        int wc = wc0 + nt * 16 + lrow;
        float bias = bvec[wc];
        #pragma unroll
        for (int reg = 0; reg < 4; reg++) {
            int gr = bm + w * 16 + quad * 4 + reg;
            if (gr < N) {
                float v = acc[nt][reg] + Wb[(size_t)(QDIM + ki[reg]) * CDIM + wc] + bias;
                if (gc < 256)      Qbuf[(size_t)gr * 256 + gc] = (_Float16)v;
                else if (gc < 512) Kbuf[(size_t)gr * 256 + (gc - 256)] = (_Float16)v;
                else if (gc < 576) Vbuf[(size_t)gr * KDIM + (gc - 512)] = (_Float16)v;
                else               Sbuf[(size_t)gr * KDIM + (gc - 576)] = v;
            }
        }
    }
}

// masked bucket scatter: read-filter on deg sentinel (unmasked ~61% skip the
// atomic AND the scattered store); adj entries are ushort (src < 65536).
__global__ __launch_bounds__(256) void scatter_kernel(
        const int* __restrict__ src, const int* __restrict__ dst,
        int* __restrict__ deg, unsigned short* __restrict__ adj, int E) {
    int e = blockIdx.x * blockDim.x + threadIdx.x;
    if (e < E) {
        int d = dst[e];
        if (deg[d] > -1000000) {              // masked nodes: deg in [0, ~80]
            int slot = atomicAdd(&deg[d], 1);
            if ((unsigned)slot < CAP) adj[(size_t)d * CAP + slot] = (unsigned short)src[e];
        }
    }
}

// 1 wave per output-run (masked node): 16-lane groups, 4 edges in flight,
// private online-softmax state per group, single end-merge,
// fused relu + 64x128 GEMV into d_out. 4 rows/block.
__global__ __launch_bounds__(256) void attend_out(
        const _Float16* __restrict__ Qbuf, const _Float16* __restrict__ Kbuf,
        const _Float16* __restrict__ Vbuf, const float* __restrict__ Sbuf,
        const int* __restrict__ deg, const unsigned short* __restrict__ adj,
        const int* __restrict__ mask, const float* __restrict__ Wo,
        const float* __restrict__ bo, float* __restrict__ out, int M) {
    int w = threadIdx.x >> 6, lane = threadIdx.x & 63;
    int r = blockIdx.x * 4 + w;
    if (r >= M) return;
    int node = mask[r];
    if (r > 0 && mask[r - 1] == node) return;   // duplicate run: start-wave writes it
    int l = lane & 15, g = lane >> 4;

    const uint4* qp = (const uint4*)(Qbuf + (size_t)node * 256 + l * 16);
    uint4 qa = qp[0], qb = qp[1];
    hf2 qh[8] = { bc_h2(qa.x), bc_h2(qa.y), bc_h2(qa.z), bc_h2(qa.w),
                  bc_h2(qb.x), bc_h2(qb.y), bc_h2(qb.z), bc_h2(qb.w) };

    int dn = min(deg[node], CAP);
    const unsigned short* arow = adj + (size_t)node * CAP;

    // private per-group state: m, dsum uniform in group; acc = 4 V-cols per lane
    float m = NEG_INF, dsum = 0.f;
    float a0 = 0.f, a1 = 0.f, a2 = 0.f, a3 = 0.f;
    for (int i = g; i < dn; i += 4) {
        int s = arow[i];
        const uint4* kp = (const uint4*)(Kbuf + (size_t)s * 256 + l * 16);
        uint4 ka = kp[0], kb = kp[1];
        float d = 0.f;
        d = dot2acc(bc_h2(ka.x), qh[0], d);
        d = dot2acc(bc_h2(ka.y), qh[1], d);
        d = dot2acc(bc_h2(ka.z), qh[2], d);
        d = dot2acc(bc_h2(ka.w), qh[3], d);
        d = dot2acc(bc_h2(kb.x), qh[4], d);
        d = dot2acc(bc_h2(kb.y), qh[5], d);
        d = dot2acc(bc_h2(kb.z), qh[6], d);
        d = dot2acc(bc_h2(kb.w), qh[7], d);
        d += __shfl_xor(d, 1, 64);
        d += __shfl_xor(d, 2, 64);
        d += __shfl_xor(d, 4, 64);
        d += __shfl_xor(d, 8, 64);
        float sc = d * 0.0625f;              // 1/sqrt(256)
        float m_new = fmaxf(m, sc);
        float scale = __expf(m - m_new);     // first edge: exp(-inf)=0
        float p = __expf(sc - m_new);
        dsum = dsum * scale + p;
        uint2 vv = *(const uint2*)(Vbuf + (size_t)s * KDIM + l * 4);
        hf2 v01 = bc_h2(vv.x), v23 = bc_h2(vv.y);
        a0 = a0 * scale + p * (float)v01[0];
        a1 = a1 * scale + p * (float)v01[1];
        a2 = a2 * scale + p * (float)v23[0];
        a3 = a3 * scale + p * (float)v23[1];
        m = m_new;
    }

    // merge the 4 groups (m, dsum group-uniform)
    float Mx = fmaxf(m, __shfl_xor(m, 16, 64));
    Mx = fmaxf(Mx, __shfl_xor(Mx, 32, 64));
    float wgt = (m == NEG_INF) ? 0.f : __expf(m - Mx);   // empty group / dn==0
    float ds = dsum * wgt;
    ds += __shfl_xor(ds, 16, 64);
    ds += __shfl_xor(ds, 32, 64);
    a0 *= wgt; a1 *= wgt; a2 *= wgt; a3 *= wgt;
    a0 += __shfl_xor(a0, 16, 64); a0 += __shfl_xor(a0, 32, 64);
    a1 += __shfl_xor(a1, 16, 64); a1 += __shfl_xor(a1, 32, 64);
    a2 += __shfl_xor(a2, 16, 64); a2 += __shfl_xor(a2, 32, 64);
    a3 += __shfl_xor(a3, 16, 64); a3 += __shfl_xor(a3, 32, 64);
    float inv = 1.f / (ds + 1e-16f);

    // h cols l*4..l*4+3 (identical across groups)
    float4 s4 = *((const float4*)(Sbuf + (size_t)node * KDIM + l * 4));
    float h0 = fmaxf(a0 * inv + s4.x, 0.f);
    float h1 = fmaxf(a1 * inv + s4.y, 0.f);
    float h2 = fmaxf(a2 * inv + s4.z, 0.f);
    float h3 = fmaxf(a3 * inv + s4.w, 0.f);

    // GEMV: out(row) = h @ Wo + bo
    float o0 = bo[lane], o1 = bo[lane + 64];
    #pragma unroll
    for (int c = 0; c < KDIM; c++) {
        float hc = (c & 3) == 0 ? h0 : (c & 3) == 1 ? h1 : (c & 3) == 2 ? h2 : h3;
        float hv = __shfl(hc, c >> 2, 64);
        o0 += hv * Wo[c * DOUT + lane];
        o1 += hv * Wo[c * DOUT + 64 + lane];
    }
    int rr = r;
    do {
        out[(size_t)rr * DOUT + lane] = o0;
        out[(size_t)rr * DOUT + 64 + lane] = o1;
        rr++;
    } while (rr < M && mask[rr] == node);
}

extern "C" void kernel_launch(void* const* d_in, const int* in_sizes, int n_in,
                              void* d_out, int out_size, void* d_ws, size_t ws_size,
                              hipStream_t stream) {
    const float* query    = (const float*)d_in[0];
    const int* key_idx    = (const int*)d_in[1];
    const int* edge_index = (const int*)d_in[2];
    const int* mask_idx   = (const int*)d_in[3];
    const float* Wq = (const float*)d_in[4];
    const float* bq = (const float*)d_in[5];
    const float* Wk = (const float*)d_in[6];
    const float* bk = (const float*)d_in[7];
    const float* Wv = (const float*)d_in[8];
    const float* bv = (const float*)d_in[9];
    const float* Ws = (const float*)d_in[10];
    const float* bs = (const float*)d_in[11];
    const float* Wo = (const float*)d_in[12];
    const float* bo = (const float*)d_in[13];

    int N = in_sizes[0] / QDIM;
    int E = in_sizes[2] / 2;
    int M = in_sizes[3];
    const int* esrc = edge_index;
    const int* edst = edge_index + E;

    char* wsb = (char*)d_ws;
    size_t off = 0;
    auto alloc = [&](size_t nbytes) { char* p = wsb + off; off += (nbytes + 15) & ~15ull; return p; };
    _Float16* Qh   = (_Float16*)alloc((size_t)N * QDIM * 2);
    _Float16* BhT  = (_Float16*)alloc((size_t)NCOLS * QDIM * 2);
    _Float16* Qbuf = (_Float16*)alloc((size_t)N * 256 * 2);
    _Float16* Kbuf = (_Float16*)alloc((size_t)N * 256 * 2);
    _Float16* Vbuf = (_Float16*)alloc((size_t)N * KDIM * 2);
    float* Sbuf    = (float*)alloc((size_t)N * KDIM * 4);
    int*   deg     = (int*)alloc((size_t)N * 4);
    unsigned short* adj = (unsigned short*)alloc((size_t)N * CAP * 2);

    int qchunks = N * QDIM / 4;   // float4 chunks of query
    int prep_elems = qchunks + NCOLS * QDIM + N;
    prep_kernel<<<(prep_elems + 255) / 256, 256, 0, stream>>>(
        query, Wq, Wk, Wv, Ws, Qh, BhT, deg, qchunks, N);

    dim3 ggrid((N + 63) / 64, 10);   // 640 cols / 64, single tile per block
    gemm_nodes<<<ggrid, 256, 0, stream>>>(Qh, BhT, key_idx, Wq, bq, Wk, bk, Wv, bv,
                                          Ws, bs, mask_idx, M, deg,
                                          Qbuf, Kbuf, Vbuf, Sbuf, N);

    scatter_kernel<<<(E + 255) / 256, 256, 0, stream>>>(esrc, edst, deg, adj, E);

    attend_out<<<(M + 3) / 4, 256, 0, stream>>>(Qbuf, Kbuf, Vbuf, Sbuf, deg, adj,
                                                mask_idx, Wo, bo, (float*)d_out, M);
}

// Round 14
// 149.416 us; speedup vs baseline: 1.0558x; 1.0349x over previous
//
#include <hip/hip_runtime.h>

#define QDIM 192
#define KDIM 64
#define CDIM 256
#define DOUT 128
#define CAP 128     // adjacency slots per node; deg ~ Poisson(32), P(>=128) ~ 1e-40
#define NEG_INF __int_as_float(0xFF800000)
#define LDP 200     // LDS row pitch in halves (192 + 8 pad)

typedef _Float16 hf2 __attribute__((ext_vector_type(2)));
typedef _Float16 half4 __attribute__((ext_vector_type(4)));
typedef _Float16 half8 __attribute__((ext_vector_type(8)));
typedef float floatx4 __attribute__((ext_vector_type(4)));

#if defined(__has_builtin)
#if __has_builtin(__builtin_amdgcn_fdot2)
#define HAVE_FDOT2 1
#endif
#endif

__device__ __forceinline__ hf2 bc_h2(unsigned u) { return __builtin_bit_cast(hf2, u); }

__device__ __forceinline__ float dot2acc(hf2 a, hf2 b, float c) {
#ifdef HAVE_FDOT2
    return __builtin_amdgcn_fdot2(a, b, c, false);
#else
    return c + (float)a[0] * (float)b[0] + (float)a[1] * (float)b[1];
#endif
}

// prep: convert query fp32 -> fp16 (vectorized) AND poison deg with INT_MIN
// (gemm piggyback sets deg[mask]=0; unmasked nodes never reach slot >= 0)
__global__ __launch_bounds__(256) void prep_kernel(
        const float* __restrict__ query, _Float16* __restrict__ Qh,
        int* __restrict__ deg, int qchunks, int N) {
    int t = blockIdx.x * blockDim.x + threadIdx.x;
    if (t < qchunks) {
        float4 v = ((const float4*)query)[t];
        half4 h = { (_Float16)v.x, (_Float16)v.y, (_Float16)v.z, (_Float16)v.w };
        ((half4*)Qh)[t] = h;
        return;
    }
    t -= qchunks;
    if (t < N) deg[t] = (int)0x80000000;
}

// MFMA node GEMM, self-contained:
//  - piggyback: deg[mask[...]] = 0
//  - A staged from fp16 Qh (uint4 loads): 64 rows x 192 halves = 1536 uint4 (24/row)
//  - B tile: contiguous-column slice of one W segment, coalesced fp32 loads
//  - epilogue adds one-hot row W[192+key_idx][.] + bias, routes Q/K/V (f16), S (f32)
__global__ __launch_bounds__(256) void gemm_nodes(
        const _Float16* __restrict__ Qh, const int* __restrict__ key_idx,
        const float* Wq, const float* bq, const float* Wk, const float* bk,
        const float* Wv, const float* bv, const float* Ws, const float* bs,
        const int* __restrict__ mask, int M, int* __restrict__ deg,
        _Float16* __restrict__ Qbuf, _Float16* __restrict__ Kbuf,
        _Float16* __restrict__ Vbuf, float* __restrict__ Sbuf, int N) {
    __shared__ __align__(16) _Float16 As[64 * LDP];
    __shared__ __align__(16) _Float16 Bs[64 * LDP];
    int bm = blockIdx.x * 64;
    int bn = blockIdx.y * 64;   // virtual col base: [q 0:256 | k 256:512 | v 512:576 | s 576:640]
    int tid = threadIdx.x;

    // piggyback masked-node marking
    int gid = (blockIdx.y * gridDim.x + blockIdx.x) * 256 + tid;
    if (gid < M) deg[mask[gid]] = 0;

    // segment for this bn-tile (block-uniform)
    const float* Wb; const float* bvec; int wc0;
    if (bn < 256)      { Wb = Wq; bvec = bq; wc0 = bn; }
    else if (bn < 512) { Wb = Wk; bvec = bk; wc0 = bn - 256; }
    else if (bn < 576) { Wb = Wv; bvec = bv; wc0 = QDIM + (bn - 512); }
    else               { Wb = Ws; bvec = bs; wc0 = QDIM + (bn - 576); }

    // A: 64 rows x 192 halves = 64 x 24 uint4 = 1536 uint4; 6 per thread
    #pragma unroll
    for (int it = 0; it < 6; it++) {
        int idx = tid + it * 256;            // 0..1535
        int r = idx / 24, q4 = idx % 24;
        int gr = bm + r;
        uint4 va = make_uint4(0u, 0u, 0u, 0u);
        if (gr < N) va = ((const uint4*)(Qh + (size_t)gr * QDIM))[q4];
        *((uint4*)&As[r * LDP + q4 * 8]) = va;
    }
    // B: cols wc0..wc0+63, rows 0..191 of Wb. lane=col => coalesced dword loads.
    {
        int c = tid & 63, r0 = tid >> 6;
        #pragma unroll
        for (int it = 0; it < 6; it++) {
            int kg = r0 + it * 4;            // 0..23 (8-row groups)
            float f[8];
            #pragma unroll
            for (int j = 0; j < 8; j++)
                f[j] = Wb[(size_t)(kg * 8 + j) * CDIM + wc0 + c];
            half8 h8 = { (_Float16)f[0], (_Float16)f[1], (_Float16)f[2], (_Float16)f[3],
                         (_Float16)f[4], (_Float16)f[5], (_Float16)f[6], (_Float16)f[7] };
            *((half8*)&Bs[c * LDP + kg * 8]) = h8;
        }
    }
    __syncthreads();

    int w = tid >> 6, l = tid & 63;
    int lrow = l & 15, quad = l >> 4;
    floatx4 acc[4] = {{0.f,0.f,0.f,0.f},{0.f,0.f,0.f,0.f},{0.f,0.f,0.f,0.f},{0.f,0.f,0.f,0.f}};

    const _Float16* arow = &As[(w * 16 + lrow) * LDP + quad * 8];
    #pragma unroll
    for (int ks = 0; ks < 6; ks++) {
        half8 af = *(const half8*)(arow + ks * 32);
        #pragma unroll
        for (int nt = 0; nt < 4; nt++) {
            half8 bf = *(const half8*)(&Bs[(nt * 16 + lrow) * LDP + quad * 8 + ks * 32]);
            acc[nt] = __builtin_amdgcn_mfma_f32_16x16x32_f16(af, bf, acc[nt], 0, 0, 0);
        }
    }

    // epilogue: D(row = bm + w*16 + quad*4 + reg, col = bn + nt*16 + lrow)
    int ki[4];
    #pragma unroll
    for (int reg = 0; reg < 4; reg++) {
        int gr = bm + w * 16 + quad * 4 + reg;
        ki[reg] = (gr < N) ? key_idx[gr] : 0;
    }
    #pragma unroll
    for (int nt = 0; nt < 4; nt++) {
        int gc = bn + nt * 16 + lrow;
        int wc = wc0 + nt * 16 + lrow;
        float bias = bvec[wc];
        #pragma unroll
        for (int reg = 0; reg < 4; reg++) {
            int gr = bm + w * 16 + quad * 4 + reg;
            if (gr < N) {
                float v = acc[nt][reg] + Wb[(size_t)(QDIM + ki[reg]) * CDIM + wc] + bias;
                if (gc < 256)      Qbuf[(size_t)gr * 256 + gc] = (_Float16)v;
                else if (gc < 512) Kbuf[(size_t)gr * 256 + (gc - 256)] = (_Float16)v;
                else if (gc < 576) Vbuf[(size_t)gr * KDIM + (gc - 512)] = (_Float16)v;
                else               Sbuf[(size_t)gr * KDIM + (gc - 576)] = v;
            }
        }
    }
}

// capped bucket scatter; deg sentinel: masked nodes start at 0, others hugely
// negative => (unsigned)slot >= CAP skips the store. adj is ushort (src < 65536):
// a deg~32 bucket is one 64B line.
__global__ __launch_bounds__(256) void scatter_kernel(
        const int* __restrict__ src, const int* __restrict__ dst,
        int* __restrict__ deg, unsigned short* __restrict__ adj, int E) {
    int e = blockIdx.x * blockDim.x + threadIdx.x;
    if (e < E) {
        int d = dst[e];
        int slot = atomicAdd(&deg[d], 1);
        if ((unsigned)slot < CAP) adj[(size_t)d * CAP + slot] = (unsigned short)src[e];
    }
}

// 1 wave per output-run (masked node): 16-lane groups, 4 edges in flight,
// private online-softmax state per group, single end-merge,
// fused relu + 64x128 GEMV into d_out. 4 rows/block.
__global__ __launch_bounds__(256) void attend_out(
        const _Float16* __restrict__ Qbuf, const _Float16* __restrict__ Kbuf,
        const _Float16* __restrict__ Vbuf, const float* __restrict__ Sbuf,
        const int* __restrict__ deg, const unsigned short* __restrict__ adj,
        const int* __restrict__ mask, const float* __restrict__ Wo,
        const float* __restrict__ bo, float* __restrict__ out, int M) {
    int w = threadIdx.x >> 6, lane = threadIdx.x & 63;
    int r = blockIdx.x * 4 + w;
    if (r >= M) return;
    int node = mask[r];
    if (r > 0 && mask[r - 1] == node) return;   // duplicate run: start-wave writes it
    int l = lane & 15, g = lane >> 4;

    const uint4* qp = (const uint4*)(Qbuf + (size_t)node * 256 + l * 16);
    uint4 qa = qp[0], qb = qp[1];
    hf2 qh[8] = { bc_h2(qa.x), bc_h2(qa.y), bc_h2(qa.z), bc_h2(qa.w),
                  bc_h2(qb.x), bc_h2(qb.y), bc_h2(qb.z), bc_h2(qb.w) };

    int dn = min(deg[node], CAP);
    const unsigned short* arow = adj + (size_t)node * CAP;

    // private per-group state: m, dsum uniform in group; acc = 4 V-cols per lane
    float m = NEG_INF, dsum = 0.f;
    float a0 = 0.f, a1 = 0.f, a2 = 0.f, a3 = 0.f;
    for (int i = g; i < dn; i += 4) {
        int s = arow[i];
        const uint4* kp = (const uint4*)(Kbuf + (size_t)s * 256 + l * 16);
        uint4 ka = kp[0], kb = kp[1];
        float d = 0.f;
        d = dot2acc(bc_h2(ka.x), qh[0], d);
        d = dot2acc(bc_h2(ka.y), qh[1], d);
        d = dot2acc(bc_h2(ka.z), qh[2], d);
        d = dot2acc(bc_h2(ka.w), qh[3], d);
        d = dot2acc(bc_h2(kb.x), qh[4], d);
        d = dot2acc(bc_h2(kb.y), qh[5], d);
        d = dot2acc(bc_h2(kb.z), qh[6], d);
        d = dot2acc(bc_h2(kb.w), qh[7], d);
        d += __shfl_xor(d, 1, 64);
        d += __shfl_xor(d, 2, 64);
        d += __shfl_xor(d, 4, 64);
        d += __shfl_xor(d, 8, 64);
        float sc = d * 0.0625f;              // 1/sqrt(256)
        float m_new = fmaxf(m, sc);
        float scale = __expf(m - m_new);     // first edge: exp(-inf)=0
        float p = __expf(sc - m_new);
        dsum = dsum * scale + p;
        uint2 vv = *(const uint2*)(Vbuf + (size_t)s * KDIM + l * 4);
        hf2 v01 = bc_h2(vv.x), v23 = bc_h2(vv.y);
        a0 = a0 * scale + p * (float)v01[0];
        a1 = a1 * scale + p * (float)v01[1];
        a2 = a2 * scale + p * (float)v23[0];
        a3 = a3 * scale + p * (float)v23[1];
        m = m_new;
    }

    // merge the 4 groups (m, dsum group-uniform)
    float Mx = fmaxf(m, __shfl_xor(m, 16, 64));
    Mx = fmaxf(Mx, __shfl_xor(Mx, 32, 64));
    float wgt = (m == NEG_INF) ? 0.f : __expf(m - Mx);   // empty group / dn==0
    float ds = dsum * wgt;
    ds += __shfl_xor(ds, 16, 64);
    ds += __shfl_xor(ds, 32, 64);
    a0 *= wgt; a1 *= wgt; a2 *= wgt; a3 *= wgt;
    a0 += __shfl_xor(a0, 16, 64); a0 += __shfl_xor(a0, 32, 64);
    a1 += __shfl_xor(a1, 16, 64); a1 += __shfl_xor(a1, 32, 64);
    a2 += __shfl_xor(a2, 16, 64); a2 += __shfl_xor(a2, 32, 64);
    a3 += __shfl_xor(a3, 16, 64); a3 += __shfl_xor(a3, 32, 64);
    float inv = 1.f / (ds + 1e-16f);

    // h cols l*4..l*4+3 (identical across groups)
    float4 s4 = *((const float4*)(Sbuf + (size_t)node * KDIM + l * 4));
    float h0 = fmaxf(a0 * inv + s4.x, 0.f);
    float h1 = fmaxf(a1 * inv + s4.y, 0.f);
    float h2 = fmaxf(a2 * inv + s4.z, 0.f);
    float h3 = fmaxf(a3 * inv + s4.w, 0.f);

    // GEMV: out(row) = h @ Wo + bo
    float o0 = bo[lane], o1 = bo[lane + 64];
    #pragma unroll
    for (int c = 0; c < KDIM; c++) {
        float hc = (c & 3) == 0 ? h0 : (c & 3) == 1 ? h1 : (c & 3) == 2 ? h2 : h3;
        float hv = __shfl(hc, c >> 2, 64);
        o0 += hv * Wo[c * DOUT + lane];
        o1 += hv * Wo[c * DOUT + 64 + lane];
    }
    int rr = r;
    do {
        out[(size_t)rr * DOUT + lane] = o0;
        out[(size_t)rr * DOUT + 64 + lane] = o1;
        rr++;
    } while (rr < M && mask[rr] == node);
}

extern "C" void kernel_launch(void* const* d_in, const int* in_sizes, int n_in,
                              void* d_out, int out_size, void* d_ws, size_t ws_size,
                              hipStream_t stream) {
    const float* query    = (const float*)d_in[0];
    const int* key_idx    = (const int*)d_in[1];
    const int* edge_index = (const int*)d_in[2];
    const int* mask_idx   = (const int*)d_in[3];
    const float* Wq = (const float*)d_in[4];
    const float* bq = (const float*)d_in[5];
    const float* Wk = (const float*)d_in[6];
    const float* bk = (const float*)d_in[7];
    const float* Wv = (const float*)d_in[8];
    const float* bv = (const float*)d_in[9];
    const float* Ws = (const float*)d_in[10];
    const float* bs = (const float*)d_in[11];
    const float* Wo = (const float*)d_in[12];
    const float* bo = (const float*)d_in[13];

    int N = in_sizes[0] / QDIM;
    int E = in_sizes[2] / 2;
    int M = in_sizes[3];
    const int* esrc = edge_index;
    const int* edst = edge_index + E;

    char* wsb = (char*)d_ws;
    size_t off = 0;
    auto alloc = [&](size_t nbytes) { char* p = wsb + off; off += (nbytes + 15) & ~15ull; return p; };
    _Float16* Qh   = (_Float16*)alloc((size_t)N * QDIM * 2);
    _Float16* Qbuf = (_Float16*)alloc((size_t)N * 256 * 2);
    _Float16* Kbuf = (_Float16*)alloc((size_t)N * 256 * 2);
    _Float16* Vbuf = (_Float16*)alloc((size_t)N * KDIM * 2);
    float* Sbuf    = (float*)alloc((size_t)N * KDIM * 4);
    int*   deg     = (int*)alloc((size_t)N * 4);
    unsigned short* adj = (unsigned short*)alloc((size_t)N * CAP * 2);

    int qchunks = N * QDIM / 4;   // float4 chunks of query
    prep_kernel<<<(qchunks + N + 255) / 256, 256, 0, stream>>>(query, Qh, deg, qchunks, N);

    dim3 ggrid((N + 63) / 64, 10);                   // 640 cols / 64
    gemm_nodes<<<ggrid, 256, 0, stream>>>(Qh, key_idx, Wq, bq, Wk, bk, Wv, bv,
                                          Ws, bs, mask_idx, M, deg,
                                          Qbuf, Kbuf, Vbuf, Sbuf, N);

    scatter_kernel<<<(E + 255) / 256, 256, 0, stream>>>(esrc, edst, deg, adj, E);

    attend_out<<<(M + 3) / 4, 256, 0, stream>>>(Qbuf, Kbuf, Vbuf, Sbuf, deg, adj,
                                                mask_idx, Wo, bo, (float*)d_out, M);
}